// Round 7
// baseline (410.764 us; speedup 1.0000x reference)
//
#include <hip/hip_runtime.h>
#include <hip/hip_bf16.h>
#include <math.h>

typedef __bf16 bf16t;
typedef __bf16 bf8v __attribute__((ext_vector_type(8)));
typedef float  f4v  __attribute__((ext_vector_type(4)));
typedef unsigned int u32;
typedef u32 u4v __attribute__((ext_vector_type(4)));

#define DD  4
#define FF  64
#define HH  128
#define FIN 129
#define MT  64    // rows per block; 16 rows per wave; waves fully independent

// ---- weight prep: f32 -> bf16, transposed to [n][k] for fragment loads ----
// Layout [d][n][k] means the A-fragment for mfma_16x16x32 (lane l15 = row n,
// k = K*32 + q*8 + u) is a contiguous 16B chunk -> one global_load_dwordx4.
__global__ void prep_weights(const float* __restrict__ w1,
                             const float* __restrict__ w2,
                             const float* __restrict__ w3,
                             bf16t* __restrict__ w1t,
                             bf16t* __restrict__ w2t,
                             bf16t* __restrict__ w3t,
                             float* __restrict__ w1last) {
  int i = blockIdx.x * blockDim.x + threadIdx.x;
  if (i < DD * HH * HH) {            // 65536: w1t + w2t
    int d = i >> 14, n = (i >> 7) & 127, k = i & 127;
    w1t[i] = (bf16t)w1[(d * FIN + k) * HH + n];
    w2t[i] = (bf16t)w2[(d * HH + k) * HH + n];
  }
  if (i < HH * HH) {                 // 16384: w3t
    int n = i >> 7, k = i & 127;
    w3t[i] = (bf16t)w3[k * HH + n];
  }
  if (i < DD * HH) {                 // 512: last feat column of w1, kept f32
    int d = i >> 7, n = i & 127;
    w1last[i] = w1[(d * FIN + 128) * HH + n];
  }
}

__device__ __forceinline__ u32 pack2(float a, float b) {
  union { bf16t h; unsigned short u; } ua, ub;
  ua.h = (bf16t)a; ub.h = (bf16t)b;
  return ((u32)ub.u << 16) | (u32)ua.u;
}

// In-register transpose: h[nt][r] = x[hidden=16nt+4q+r][batch l15] (f32) ->
// bb[K] = B-fragment for 16x16x32 mfma: element u = x[k=32K+8q+u][l15], bf16.
// src lane = l15 + 16*((2q+(u>>2))&3); src reg pair selected by q>=2.
__device__ __forceinline__ void xpose_pack(const f4v (&h)[8], bf8v (&bb)[4],
                                           int l15, int q) {
  const int lA = l15 + 16 * ((2 * q) & 3);       // for u<4
  const int lB = l15 + 16 * ((2 * q + 1) & 3);   // for u>=4
  const bool hiq = (q >= 2);
  #pragma unroll
  for (int K = 0; K < 4; ++K) {
    u32 pa0 = pack2(h[2 * K][0],     h[2 * K][1]);
    u32 pa1 = pack2(h[2 * K][2],     h[2 * K][3]);
    u32 pb0 = pack2(h[2 * K + 1][0], h[2 * K + 1][1]);
    u32 pb1 = pack2(h[2 * K + 1][2], h[2 * K + 1][3]);
    u32 w0a = __shfl(pa0, lA), w0b = __shfl(pb0, lA);
    u32 w1a = __shfl(pa1, lA), w1b = __shfl(pb1, lA);
    u32 w2a = __shfl(pa0, lB), w2b = __shfl(pb0, lB);
    u32 w3a = __shfl(pa1, lB), w3b = __shfl(pb1, lB);
    u4v wv;
    wv.x = hiq ? w0b : w0a;
    wv.y = hiq ? w1b : w1a;
    wv.z = hiq ? w2b : w2a;
    wv.w = hiq ? w3b : w3a;
    union { u4v w; bf8v v; } cv;
    cv.w = wv;
    bb[K] = cv.v;
  }
}

// No LDS, no barriers: weights are read as A-fragments directly from global
// (L1/L2-resident; each wave reads each byte exactly once -> staging in LDS
// only amortized across 4 waves, at the cost of 18 block-wide vmcnt(0)
// barriers = the measured convoy. R3/R5/R6 all plateaued at 97-101 us.)
__launch_bounds__(256, 2)
__global__ void fourier_mlp(
    const float* __restrict__ cont,   // [N,4]
    const float* __restrict__ freqs,  // [4,64]
    const float* __restrict__ b1,     // [4,128]
    const float* __restrict__ ln1g,
    const float* __restrict__ ln1b,
    const float* __restrict__ b2,
    const float* __restrict__ outg,   // [128]
    const float* __restrict__ outb,
    const float* __restrict__ b3,
    const bf16t* __restrict__ w1t,    // [4][128][128] bf16, [d][n][k]
    const bf16t* __restrict__ w2t,    // [4][128][128]
    const bf16t* __restrict__ w3t,    // [128][128]
    const float* __restrict__ w1last, // [4][128]
    float* __restrict__ out)          // [N,128] f32
{
  const int tid  = threadIdx.x;
  const int lane = tid & 63;
  const int wave = tid >> 6;        // 0..3 (independent; no cross-wave state)
  const int q    = lane >> 4;
  const int l15  = lane & 15;
  const int row0 = blockIdx.x * MT + wave * 16;  // wave's 16-row slab

  // cont for this wave's 16 rows, all 4 dims (one 16B load)
  const f4v call = *(const f4v*)&cont[(row0 + l15) * DD];

  const f4v fzero = {0.0f, 0.0f, 0.0f, 0.0f};
  f4v emb[8];   // emb[hidden 16nt+4q+r][batch l15], accumulated over d
  #pragma unroll
  for (int nt = 0; nt < 8; ++nt) emb[nt] = fzero;

  for (int d = 0; d < DD; ++d) {
    // ===== trig B-frags (in-register Fourier features) =====
    // K: 0 = cos half0, 1 = cos half1, 2 = sin half0, 3 = sin half1
    bf8v fB[4];
    {
      const float c = call[d];
      #pragma unroll
      for (int hf = 0; hf < 2; ++hf) {
        f4v f0 = *(const f4v*)&freqs[d * FF + hf * 32 + q * 8];
        f4v f1 = *(const f4v*)&freqs[d * FF + hf * 32 + q * 8 + 4];
        #pragma unroll
        for (int u = 0; u < 8; ++u) {
          float fv = (u < 4) ? f0[u] : f1[u - 4];
          float a = c * fv;
          float t = a - floorf(a);   // revolutions: sin/cos(2*pi*t)
          fB[hf][u]     = (bf16t)__builtin_amdgcn_cosf(t);
          fB[2 + hf][u] = (bf16t)__builtin_amdgcn_sinf(t);
        }
      }
    }

    // ===== GEMM1: acc[m=hidden][n=batch] = w1t(A, from global) * feat(B) =====
    const bf16t* w1d = w1t + d * HH * HH;
    f4v acc[8];
    #pragma unroll
    for (int nt = 0; nt < 8; ++nt) acc[nt] = fzero;
    #pragma unroll
    for (int K = 0; K < 4; ++K)
      #pragma unroll
      for (int nt = 0; nt < 8; ++nt) {
        bf8v wf = *(const bf8v*)&w1d[(nt * 16 + l15) * HH + K * 32 + q * 8];
        acc[nt] = __builtin_amdgcn_mfma_f32_16x16x32_bf16(wf, fB[K], acc[nt], 0, 0, 0);
      }

    // ===== epilogue: + b1 + rank-1 (f32 exact), LN, ReLU, xpose =====
    bf8v bB[4];
    {
      const float c = call[d];
      float s = 0.0f, ss = 0.0f;
      #pragma unroll
      for (int nt = 0; nt < 8; ++nt) {
        f4v b1v = *(const f4v*)&b1[d * HH + nt * 16 + q * 4];
        f4v w1l = *(const f4v*)&w1last[d * HH + nt * 16 + q * 4];
        #pragma unroll
        for (int r = 0; r < 4; ++r) {
          float v = acc[nt][r] + b1v[r] + c * w1l[r];  // + b1 + rank-1, f32
          acc[nt][r] = v;
          s += v; ss += v * v;
        }
      }
      s  += __shfl_xor(s, 16);  s  += __shfl_xor(s, 32);
      ss += __shfl_xor(ss, 16); ss += __shfl_xor(ss, 32);
      float mu   = s * (1.0f / 128.0f);
      float var  = ss * (1.0f / 128.0f) - mu * mu;
      float rstd = rsqrtf(var + 1e-5f);
      #pragma unroll
      for (int nt = 0; nt < 8; ++nt) {
        f4v gv = *(const f4v*)&ln1g[d * HH + nt * 16 + q * 4];
        f4v bv = *(const f4v*)&ln1b[d * HH + nt * 16 + q * 4];
        #pragma unroll
        for (int r = 0; r < 4; ++r) {
          float v = (acc[nt][r] - mu) * rstd * gv[r] + bv[r];
          acc[nt][r] = fmaxf(v, 0.0f);
        }
      }
      xpose_pack(acc, bB, l15, q);
    }

    // ===== GEMM2: emb += w2t(A, from global) * h_relu(B) =====
    const bf16t* w2d = w2t + d * HH * HH;
    #pragma unroll
    for (int K = 0; K < 4; ++K)
      #pragma unroll
      for (int nt = 0; nt < 8; ++nt) {
        bf8v wf = *(const bf8v*)&w2d[(nt * 16 + l15) * HH + K * 32 + q * 8];
        emb[nt] = __builtin_amdgcn_mfma_f32_16x16x32_bf16(wf, bB[K], emb[nt], 0, 0, 0);
      }
    // + b2[d]  (global, L2-resident broadcast)
    #pragma unroll
    for (int nt = 0; nt < 8; ++nt) {
      f4v b2v = *(const f4v*)&b2[d * HH + nt * 16 + q * 4];
      emb[nt] += b2v;
    }
  } // d loop

  // ===== final LN + ReLU (registers) ; GEMM3 (w3 from global) ; store =====
  bf8v bB[4];
  {
    float s = 0.0f, ss = 0.0f;
    #pragma unroll
    for (int nt = 0; nt < 8; ++nt)
      #pragma unroll
      for (int r = 0; r < 4; ++r) {
        float v = emb[nt][r];
        s += v; ss += v * v;
      }
    s  += __shfl_xor(s, 16);  s  += __shfl_xor(s, 32);
    ss += __shfl_xor(ss, 16); ss += __shfl_xor(ss, 32);
    float mu   = s * (1.0f / 128.0f);
    float var  = ss * (1.0f / 128.0f) - mu * mu;
    float rstd = rsqrtf(var + 1e-5f);
    #pragma unroll
    for (int nt = 0; nt < 8; ++nt) {
      f4v gv = *(const f4v*)&outg[nt * 16 + q * 4];
      f4v bv = *(const f4v*)&outb[nt * 16 + q * 4];
      #pragma unroll
      for (int r = 0; r < 4; ++r) {
        float v = (emb[nt][r] - mu) * rstd * gv[r] + bv[r];
        emb[nt][r] = fmaxf(v, 0.0f);
      }
    }
    xpose_pack(emb, bB, l15, q);
  }

  f4v acc[8];
  #pragma unroll
  for (int nt = 0; nt < 8; ++nt) acc[nt] = fzero;
  #pragma unroll
  for (int K = 0; K < 4; ++K)
    #pragma unroll
    for (int nt = 0; nt < 8; ++nt) {
      bf8v wf = *(const bf8v*)&w3t[(nt * 16 + l15) * HH + K * 32 + q * 8];
      acc[nt] = __builtin_amdgcn_mfma_f32_16x16x32_bf16(wf, bB[K], acc[nt], 0, 0, 0);
    }

  #pragma unroll
  for (int nt = 0; nt < 8; ++nt) {
    f4v b3v = *(const f4v*)&b3[nt * 16 + q * 4];
    f4v o = acc[nt] + b3v;
    *(f4v*)&out[(row0 + l15) * HH + nt * 16 + q * 4] = o;
  }
}

extern "C" void kernel_launch(void* const* d_in, const int* in_sizes, int n_in,
                              void* d_out, int out_size, void* d_ws, size_t ws_size,
                              hipStream_t stream) {
  const float* cont  = (const float*)d_in[0];
  const float* freqs = (const float*)d_in[1];
  const float* w1    = (const float*)d_in[2];
  const float* b1    = (const float*)d_in[3];
  const float* ln1g  = (const float*)d_in[4];
  const float* ln1b  = (const float*)d_in[5];
  const float* w2    = (const float*)d_in[6];
  const float* b2    = (const float*)d_in[7];
  const float* outg  = (const float*)d_in[8];
  const float* outb  = (const float*)d_in[9];
  const float* w3    = (const float*)d_in[10];
  const float* b3    = (const float*)d_in[11];
  float* out = (float*)d_out;

  // ws layout: w1t[65536] bf16 | w2t[65536] bf16 | w3t[16384] bf16 | w1last[512] f32
  bf16t* w1t = (bf16t*)d_ws;
  bf16t* w2t = w1t + DD * HH * HH;
  bf16t* w3t = w2t + DD * HH * HH;
  float* w1last = (float*)((char*)d_ws + (2 * DD * HH * HH + HH * HH) * sizeof(bf16t));

  prep_weights<<<(DD * HH * HH + 255) / 256, 256, 0, stream>>>(
      w1, w2, w3, w1t, w2t, w3t, w1last);

  int n_rows = in_sizes[0] / DD;       // 131072
  int grid = n_rows / MT;              // 2048
  fourier_mlp<<<grid, 256, 0, stream>>>(
      cont, freqs, b1, ln1g, ln1b, b2, outg, outb, b3,
      w1t, w2t, w3t, w1last, out);
}

// Round 8
// 165.806 us; speedup vs baseline: 2.4774x; 2.4774x over previous
//
#include <hip/hip_runtime.h>
#include <hip/hip_bf16.h>
#include <math.h>

typedef __bf16 bf16t;
typedef __bf16 bf8v __attribute__((ext_vector_type(8)));
typedef float  f4v  __attribute__((ext_vector_type(4)));
typedef unsigned int u32;
typedef u32 u4v __attribute__((ext_vector_type(4)));

#define DD  4
#define FF  64
#define HH  128
#define FIN 129
#define MT  128   // rows per block; 32 rows per wave (g=2)

#define AS1 __attribute__((address_space(1)))
#define AS3 __attribute__((address_space(3)))

// param LDS offsets (f32 elements) — FULL set (keeps the main loop free of
// global VMEM loads so hand-counted vmcnt() is exact)
#define P_FREQS 0      // [4][64]
#define P_B1    256    // [4][128]
#define P_W1L   768    // [4][128]
#define P_G1    1280   // [4][128]
#define P_BB1   1792   // [4][128]
#define P_B2    2304   // [4][128]
#define P_OG    2816   // [128]
#define P_OB    2944   // [128]
#define P_B3    3072   // [128]
#define P_TOT   3200   // 12.8 KB; total LDS = 64 KB (2 bufs) + 12.8 KB = 76.8 KB

// XOR-swizzled LDS index: element [row][k] of a row-major [*][128] bf16 tile,
// 16B chunk (k>>3) XORed with (row&7) -> conflict-free ds_read_b128 at pitch 128.
__device__ __forceinline__ int swz(int row, int k) {
  return row * HH + ((((k >> 3) ^ (row & 7)) << 3) | (k & 7));
}

// ---- weight prep: f32 -> bf16, transposed to [n][k] for fragment loads ----
__global__ void prep_weights(const float* __restrict__ w1,
                             const float* __restrict__ w2,
                             const float* __restrict__ w3,
                             bf16t* __restrict__ w1t,
                             bf16t* __restrict__ w2t,
                             bf16t* __restrict__ w3t,
                             float* __restrict__ w1last) {
  int i = blockIdx.x * blockDim.x + threadIdx.x;
  if (i < DD * HH * HH) {            // 65536: w1t + w2t
    int d = i >> 14, n = (i >> 7) & 127, k = i & 127;
    w1t[i] = (bf16t)w1[(d * FIN + k) * HH + n];
    w2t[i] = (bf16t)w2[(d * HH + k) * HH + n];
  }
  if (i < HH * HH) {                 // 16384: w3t
    int n = i >> 7, k = i & 127;
    w3t[i] = (bf16t)w3[k * HH + n];
  }
  if (i < DD * HH) {                 // 512: last feat column of w1, kept f32
    int d = i >> 7, n = i & 127;
    w1last[i] = w1[(d * FIN + 128) * HH + n];
  }
}

// Async stage of a 128x128 bf16 [n][k] tile into swizzled LDS via
// global_load_lds (width 16). LDS dest LINEAR; XOR swizzle applied to the
// GLOBAL source chunk (both-sides-or-neither). Exactly 8 VMEM ops per wave —
// the counted s_waitcnt vmcnt(8) in the main loop relies on this.
__device__ __forceinline__ void stage_w_async(const bf16t* __restrict__ w,
                                              bf16t* __restrict__ ldsW,
                                              int tid, int wave) {
  int g0 = (tid & ~15) | ((tid & 15) ^ ((tid >> 4) & 7));
  const bf16t* src = w + g0 * 8;            // 16B source chunk (permuted)
  bf16t* dst = ldsW + wave * 64 * 8;        // wave-uniform 16B-chunk base
  #pragma unroll
  for (int j = 0; j < 8; ++j) {
    __builtin_amdgcn_global_load_lds((const AS1 void*)(src + j * 2048),
                                     (AS3 void*)(dst + j * 2048), 16, 0, 0);
  }
}

__device__ __forceinline__ u32 pack2(float a, float b) {
  union { bf16t h; unsigned short u; } ua, ub;
  ua.h = (bf16t)a; ub.h = (bf16t)b;
  return ((u32)ub.u << 16) | (u32)ua.u;
}

// In-register transpose: h[nt][r] = x[hidden=16nt+4q+r][batch l15] (f32) ->
// bb[K] = B-fragment for 16x16x32 mfma: element u = x[k=32K+8q+u][l15], bf16.
__device__ __forceinline__ void xpose_pack(const f4v (&h)[8], bf8v (&bb)[4],
                                           int l15, int q) {
  const int lA = l15 + 16 * ((2 * q) & 3);       // for u<4
  const int lB = l15 + 16 * ((2 * q + 1) & 3);   // for u>=4
  const bool hiq = (q >= 2);
  #pragma unroll
  for (int K = 0; K < 4; ++K) {
    u32 pa0 = pack2(h[2 * K][0],     h[2 * K][1]);
    u32 pa1 = pack2(h[2 * K][2],     h[2 * K][3]);
    u32 pb0 = pack2(h[2 * K + 1][0], h[2 * K + 1][1]);
    u32 pb1 = pack2(h[2 * K + 1][2], h[2 * K + 1][3]);
    u32 w0a = __shfl(pa0, lA), w0b = __shfl(pb0, lA);
    u32 w1a = __shfl(pa1, lA), w1b = __shfl(pb1, lA);
    u32 w2a = __shfl(pa0, lB), w2b = __shfl(pb0, lB);
    u32 w3a = __shfl(pa1, lB), w3b = __shfl(pb1, lB);
    u4v wv;
    wv.x = hiq ? w0b : w0a;
    wv.y = hiq ? w1b : w1a;
    wv.z = hiq ? w2b : w2a;
    wv.w = hiq ? w3b : w3a;
    union { u4v w; bf8v v; } cv;
    cv.w = wv;
    bb[K] = cv.v;
  }
}

// Counted-vmcnt sync: wait until at most N of THIS wave's VMEM ops are
// outstanding (the younger N stay in flight), then raw barrier. The pairing
// guarantees every wave's older stage landed; no full drain in the loop.
#define VM_SYNC(N) do {                                        \
    asm volatile("s_waitcnt vmcnt(" #N ")" ::: "memory");      \
    __builtin_amdgcn_s_barrier();                              \
  } while (0)
#define BAR() __builtin_amdgcn_s_barrier()

__launch_bounds__(256, 2)
__global__ void fourier_mlp(
    const float* __restrict__ cont,   // [N,4]
    const float* __restrict__ freqs,  // [4,64]
    const float* __restrict__ b1,     // [4,128]
    const float* __restrict__ ln1g,
    const float* __restrict__ ln1b,
    const float* __restrict__ b2,
    const float* __restrict__ outg,   // [128]
    const float* __restrict__ outb,
    const float* __restrict__ b3,
    const bf16t* __restrict__ w1t,    // [4][128][128] bf16, [d][n][k]
    const bf16t* __restrict__ w2t,    // [4][128][128]
    const bf16t* __restrict__ w3t,    // [128][128]
    const float* __restrict__ w1last, // [4][128]
    float* __restrict__ out)          // [N,128] f32
{
  __shared__ __align__(16) bf16t ldsW0[HH * HH];  // 32 KB: w1[d] / w3
  __shared__ __align__(16) bf16t ldsW1[HH * HH];  // 32 KB: w2[d]
  __shared__ __align__(16) float ldsP[P_TOT];     // 12.8 KB: small params

  const int tid  = threadIdx.x;
  const int lane = tid & 63;
  const int wave = tid >> 6;        // 0..3
  const int q    = lane >> 4;
  const int l15  = lane & 15;
  const int rowbase = blockIdx.x * MT;
  const int wrow = wave * 32;       // wave's 32-row slab (2 groups of 16)

  // ---- prologue: w1[0] -> ldsW0 (async), params -> ldsP, cont -> regs ----
  // cont loads FIRST so the loop's vmcnt counts are purely DMA.
  f4v call[2];
  call[0] = *(const f4v*)&cont[(rowbase + wrow + l15) * DD];
  call[1] = *(const f4v*)&cont[(rowbase + wrow + 16 + l15) * DD];

  stage_w_async(w1t, ldsW0, tid, wave);
  ldsP[P_FREQS + tid] = freqs[tid];
  #pragma unroll
  for (int i = 0; i < 2; ++i) {
    int j = tid + i * 256;
    ldsP[P_B1 + j]  = b1[j];
    ldsP[P_W1L + j] = w1last[j];
    ldsP[P_G1 + j]  = ln1g[j];
    ldsP[P_BB1 + j] = ln1b[j];
    ldsP[P_B2 + j]  = b2[j];
  }
  if (tid < 128) {
    ldsP[P_OG + tid] = outg[tid];
    ldsP[P_OB + tid] = outb[tid];
    ldsP[P_B3 + tid] = b3[tid];
  }

  const f4v fzero = {0.0f, 0.0f, 0.0f, 0.0f};
  f4v emb[2][8];   // emb[hidden 16nt+4q+r][batch l15], accumulated over d
  #pragma unroll
  for (int g = 0; g < 2; ++g)
    #pragma unroll
    for (int nt = 0; nt < 8; ++nt) emb[g][nt] = fzero;

  __syncthreads();  // full drain once: w1[0] + params + cont all ready

  for (int d = 0; d < DD; ++d) {
    // ===== issue w2[d] -> buf1, then trig (hides nothing-yet-needed) =====
    stage_w_async(w2t + d * HH * HH, ldsW1, tid, wave);  // +8 in flight

    bf8v fB[2][4];   // K: 0=cos half0, 1=cos half1, 2=sin half0, 3=sin half1
    #pragma unroll
    for (int g = 0; g < 2; ++g) {
      const float c = call[g][d];
      #pragma unroll
      for (int hf = 0; hf < 2; ++hf) {
        f4v f0 = *(const f4v*)&ldsP[P_FREQS + d * FF + hf * 32 + q * 8];
        f4v f1 = *(const f4v*)&ldsP[P_FREQS + d * FF + hf * 32 + q * 8 + 4];
        #pragma unroll
        for (int u = 0; u < 8; ++u) {
          float fv = (u < 4) ? f0[u] : f1[u - 4];
          float a = c * fv;
          float t = a - floorf(a);   // revolutions: sin/cos(2*pi*t)
          fB[g][hf][u]     = (bf16t)__builtin_amdgcn_cosf(t);
          fB[g][2 + hf][u] = (bf16t)__builtin_amdgcn_sinf(t);
        }
      }
    }
    VM_SYNC(8);  // w1[d] (older 8) landed everywhere; w2[d]'s 8 stay in flight

    // ===== GEMM1: acc = w1t(A) * feat(B), reads buf0 =====
    f4v acc[2][8];
    #pragma unroll
    for (int g = 0; g < 2; ++g)
      #pragma unroll
      for (int nt = 0; nt < 8; ++nt) acc[g][nt] = fzero;
    #pragma unroll
    for (int K = 0; K < 4; ++K)
      #pragma unroll
      for (int nt = 0; nt < 8; ++nt) {
        bf8v wf = *(const bf8v*)&ldsW0[swz(nt * 16 + l15, K * 32 + q * 8)];
        acc[0][nt] = __builtin_amdgcn_mfma_f32_16x16x32_bf16(wf, fB[0][K], acc[0][nt], 0, 0, 0);
        acc[1][nt] = __builtin_amdgcn_mfma_f32_16x16x32_bf16(wf, fB[1][K], acc[1][nt], 0, 0, 0);
      }
    BAR();  // WAR: all waves done reading buf0 (their ds_reads were consumed)

    // ===== issue next w1 (or w3) -> buf0; epilogue hides its latency =====
    stage_w_async(d < 3 ? (w1t + (d + 1) * HH * HH) : w3t, ldsW0, tid, wave);

    bf8v bB[2][4];
    #pragma unroll
    for (int g = 0; g < 2; ++g) {
      const float c = call[g][d];
      float s = 0.0f, ss = 0.0f;
      #pragma unroll
      for (int nt = 0; nt < 8; ++nt) {
        f4v b1v = *(const f4v*)&ldsP[P_B1 + d * HH + nt * 16 + q * 4];
        f4v w1l = *(const f4v*)&ldsP[P_W1L + d * HH + nt * 16 + q * 4];
        #pragma unroll
        for (int r = 0; r < 4; ++r) {
          float v = acc[g][nt][r] + b1v[r] + c * w1l[r];  // + b1 + rank-1, f32
          acc[g][nt][r] = v;
          s += v; ss += v * v;
        }
      }
      s  += __shfl_xor(s, 16);  s  += __shfl_xor(s, 32);
      ss += __shfl_xor(ss, 16); ss += __shfl_xor(ss, 32);
      float mu   = s * (1.0f / 128.0f);
      float var  = ss * (1.0f / 128.0f) - mu * mu;
      float rstd = rsqrtf(var + 1e-5f);
      #pragma unroll
      for (int nt = 0; nt < 8; ++nt) {
        f4v gv = *(const f4v*)&ldsP[P_G1 + d * HH + nt * 16 + q * 4];
        f4v bv = *(const f4v*)&ldsP[P_BB1 + d * HH + nt * 16 + q * 4];
        #pragma unroll
        for (int r = 0; r < 4; ++r) {
          float v = (acc[g][nt][r] - mu) * rstd * gv[r] + bv[r];
          acc[g][nt][r] = fmaxf(v, 0.0f);
        }
      }
      xpose_pack(acc[g], bB[g], l15, q);
    }
    VM_SYNC(8);  // w2[d] (older 8) landed; next-w1's 8 stay in flight

    // ===== GEMM2: emb += w2t(A) * h_relu(B), reads buf1 =====
    #pragma unroll
    for (int K = 0; K < 4; ++K)
      #pragma unroll
      for (int nt = 0; nt < 8; ++nt) {
        bf8v wf = *(const bf8v*)&ldsW1[swz(nt * 16 + l15, K * 32 + q * 8)];
        emb[0][nt] = __builtin_amdgcn_mfma_f32_16x16x32_bf16(wf, bB[0][K], emb[0][nt], 0, 0, 0);
        emb[1][nt] = __builtin_amdgcn_mfma_f32_16x16x32_bf16(wf, bB[1][K], emb[1][nt], 0, 0, 0);
      }
    // + b2[d]
    #pragma unroll
    for (int nt = 0; nt < 8; ++nt) {
      f4v b2v = *(const f4v*)&ldsP[P_B2 + d * HH + nt * 16 + q * 4];
      emb[0][nt] += b2v;
      emb[1][nt] += b2v;
    }
    BAR();  // WAR: all waves done reading buf1 before next d's w2 stage
  } // d loop

  // ===== final LN + ReLU (registers) ; GEMM3 (buf0 = w3) ; store =====
  bf8v bB[2][4];
  #pragma unroll
  for (int g = 0; g < 2; ++g) {
    float s = 0.0f, ss = 0.0f;
    #pragma unroll
    for (int nt = 0; nt < 8; ++nt)
      #pragma unroll
      for (int r = 0; r < 4; ++r) {
        float v = emb[g][nt][r];
        s += v; ss += v * v;
      }
    s  += __shfl_xor(s, 16);  s  += __shfl_xor(s, 32);
    ss += __shfl_xor(ss, 16); ss += __shfl_xor(ss, 32);
    float mu   = s * (1.0f / 128.0f);
    float var  = ss * (1.0f / 128.0f) - mu * mu;
    float rstd = rsqrtf(var + 1e-5f);
    #pragma unroll
    for (int nt = 0; nt < 8; ++nt) {
      f4v gv = *(const f4v*)&ldsP[P_OG + nt * 16 + q * 4];
      f4v bv = *(const f4v*)&ldsP[P_OB + nt * 16 + q * 4];
      #pragma unroll
      for (int r = 0; r < 4; ++r) {
        float v = (emb[g][nt][r] - mu) * rstd * gv[r] + bv[r];
        emb[g][nt][r] = fmaxf(v, 0.0f);
      }
    }
    xpose_pack(emb[g], bB[g], l15, q);
  }
  VM_SYNC(0);  // drain w3 (only epilogue stores follow; full drain is fine here)

  f4v acc[2][8];
  #pragma unroll
  for (int g = 0; g < 2; ++g)
    #pragma unroll
    for (int nt = 0; nt < 8; ++nt) acc[g][nt] = fzero;
  #pragma unroll
  for (int K = 0; K < 4; ++K)
    #pragma unroll
    for (int nt = 0; nt < 8; ++nt) {
      bf8v wf = *(const bf8v*)&ldsW0[swz(nt * 16 + l15, K * 32 + q * 8)];
      acc[0][nt] = __builtin_amdgcn_mfma_f32_16x16x32_bf16(wf, bB[0][K], acc[0][nt], 0, 0, 0);
      acc[1][nt] = __builtin_amdgcn_mfma_f32_16x16x32_bf16(wf, bB[1][K], acc[1][nt], 0, 0, 0);
    }

  #pragma unroll
  for (int nt = 0; nt < 8; ++nt) {
    f4v b3v = *(const f4v*)&ldsP[P_B3 + nt * 16 + q * 4];
    #pragma unroll
    for (int g = 0; g < 2; ++g) {
      f4v o = acc[g][nt] + b3v;
      *(f4v*)&out[(rowbase + wrow + g * 16 + l15) * HH + nt * 16 + q * 4] = o;
    }
  }
}

extern "C" void kernel_launch(void* const* d_in, const int* in_sizes, int n_in,
                              void* d_out, int out_size, void* d_ws, size_t ws_size,
                              hipStream_t stream) {
  const float* cont  = (const float*)d_in[0];
  const float* freqs = (const float*)d_in[1];
  const float* w1    = (const float*)d_in[2];
  const float* b1    = (const float*)d_in[3];
  const float* ln1g  = (const float*)d_in[4];
  const float* ln1b  = (const float*)d_in[5];
  const float* w2    = (const float*)d_in[6];
  const float* b2    = (const float*)d_in[7];
  const float* outg  = (const float*)d_in[8];
  const float* outb  = (const float*)d_in[9];
  const float* w3    = (const float*)d_in[10];
  const float* b3    = (const float*)d_in[11];
  float* out = (float*)d_out;

  // ws layout: w1t[65536] bf16 | w2t[65536] bf16 | w3t[16384] bf16 | w1last[512] f32
  bf16t* w1t = (bf16t*)d_ws;
  bf16t* w2t = w1t + DD * HH * HH;
  bf16t* w3t = w2t + DD * HH * HH;
  float* w1last = (float*)((char*)d_ws + (2 * DD * HH * HH + HH * HH) * sizeof(bf16t));

  prep_weights<<<(DD * HH * HH + 255) / 256, 256, 0, stream>>>(
      w1, w2, w3, w1t, w2t, w3t, w1last);

  int n_rows = in_sizes[0] / DD;       // 131072
  int grid = n_rows / MT;              // 1024
  fourier_mlp<<<grid, 256, 0, stream>>>(
      cont, freqs, b1, ln1g, ln1b, b2, outg, outb, b3,
      w1t, w2t, w3t, w1last, out);
}